// Round 1
// baseline (7216.656 us; speedup 1.0000x reference)
//
#include <hip/hip_runtime.h>
#include <math.h>

// Problem constants
#define B_  4
#define L_  2048
#define D_  1024
#define H_  16
#define HD_ 64

// ---------------------------------------------------------------------------
// GEMM: C[M,N] = A[M,K] @ W[K,N] + bias[N]     (all fp32, row-major)
// 128x128 block tile, BK=16, 256 threads, 8x8 micro-tile per thread.
// ---------------------------------------------------------------------------
#define GBM 128
#define GBN 128
#define GBK 16

__global__ __launch_bounds__(256) void gemm_bias_kernel(
    const float* __restrict__ A, const float* __restrict__ W,
    const float* __restrict__ bias, float* __restrict__ C,
    int M, int N, int K)
{
    __shared__ __align__(16) float As[GBK][GBM + 4];  // transposed A tile
    __shared__ __align__(16) float Bs[GBK][GBN + 4];

    const int tid = threadIdx.x;
    const int m0 = blockIdx.y * GBM;
    const int n0 = blockIdx.x * GBN;
    const int tx = tid & 15;   // 0..15 -> 8 cols each
    const int ty = tid >> 4;   // 0..15 -> 8 rows each

    float acc[8][8];
    #pragma unroll
    for (int i = 0; i < 8; ++i)
        #pragma unroll
        for (int j = 0; j < 8; ++j) acc[i][j] = 0.f;

    // A-tile load mapping: 128 rows x 16 cols = 512 float4, 2 per thread
    const int ar0 = tid >> 2;                const int as0 = (tid & 3) << 2;
    const int ar1 = (tid + 256) >> 2;        const int as1 = as0;  // (v&3) same
    // B-tile load mapping: 16 rows x 128 cols = 512 float4, 2 per thread
    const int br0 = tid >> 5;                const int bc0 = (tid & 31) << 2;
    const int br1 = (tid + 256) >> 5;        const int bc1 = bc0;

    for (int k0 = 0; k0 < K; k0 += GBK) {
        float4 a0 = *(const float4*)&A[(size_t)(m0 + ar0) * K + k0 + as0];
        float4 a1 = *(const float4*)&A[(size_t)(m0 + ar1) * K + k0 + as1];
        float4 b0 = *(const float4*)&W[(size_t)(k0 + br0) * N + n0 + bc0];
        float4 b1 = *(const float4*)&W[(size_t)(k0 + br1) * N + n0 + bc1];

        __syncthreads();  // previous iteration's LDS reads complete
        As[as0 + 0][ar0] = a0.x; As[as0 + 1][ar0] = a0.y;
        As[as0 + 2][ar0] = a0.z; As[as0 + 3][ar0] = a0.w;
        As[as1 + 0][ar1] = a1.x; As[as1 + 1][ar1] = a1.y;
        As[as1 + 2][ar1] = a1.z; As[as1 + 3][ar1] = a1.w;
        *(float4*)&Bs[br0][bc0] = b0;
        *(float4*)&Bs[br1][bc1] = b1;
        __syncthreads();

        #pragma unroll
        for (int kk = 0; kk < GBK; ++kk) {
            float av[8], bv[8];
            *(float4*)&av[0] = *(const float4*)&As[kk][ty * 8];
            *(float4*)&av[4] = *(const float4*)&As[kk][ty * 8 + 4];
            *(float4*)&bv[0] = *(const float4*)&Bs[kk][tx * 8];
            *(float4*)&bv[4] = *(const float4*)&Bs[kk][tx * 8 + 4];
            #pragma unroll
            for (int i = 0; i < 8; ++i)
                #pragma unroll
                for (int j = 0; j < 8; ++j)
                    acc[i][j] = fmaf(av[i], bv[j], acc[i][j]);
        }
    }

    // epilogue: add bias, store
    #pragma unroll
    for (int i = 0; i < 8; ++i) {
        const size_t row = (size_t)(m0 + ty * 8 + i) * N + n0 + tx * 8;
        float4 o0, o1;
        o0.x = acc[i][0] + bias[n0 + tx * 8 + 0];
        o0.y = acc[i][1] + bias[n0 + tx * 8 + 1];
        o0.z = acc[i][2] + bias[n0 + tx * 8 + 2];
        o0.w = acc[i][3] + bias[n0 + tx * 8 + 3];
        o1.x = acc[i][4] + bias[n0 + tx * 8 + 4];
        o1.y = acc[i][5] + bias[n0 + tx * 8 + 5];
        o1.z = acc[i][6] + bias[n0 + tx * 8 + 6];
        o1.w = acc[i][7] + bias[n0 + tx * 8 + 7];
        *(float4*)&C[row]     = o0;
        *(float4*)&C[row + 4] = o1;
    }
}

// ---------------------------------------------------------------------------
// Flash-style attention. One 64-thread block per (b, h, 64-query tile).
// Each thread owns one query row: q[64] and o[64] in VGPRs, online softmax
// per-thread (no cross-lane reductions needed). K/V/mask tiles in LDS.
// Q,K,V,ctx layout: [B, L, H*HD] (head h's slice is contiguous 64 floats).
// ---------------------------------------------------------------------------
#define BQ  64
#define BKT 64

__global__ __launch_bounds__(64) void attn_kernel(
    const float* __restrict__ Q, const float* __restrict__ K,
    const float* __restrict__ V, const int* __restrict__ mask,
    float* __restrict__ ctx)
{
    __shared__ __align__(16) float Ks[BKT][HD_ + 4];
    __shared__ __align__(16) float Vs[BKT][HD_ + 4];
    __shared__ __align__(16) int   Ms[BQ][BKT + 4];

    const int tid = threadIdx.x;
    const int q0  = blockIdx.x * BQ;
    const int h   = blockIdx.y;
    const int b   = blockIdx.z;

    const size_t qrow = ((size_t)(b * L_ + q0 + tid)) * D_ + h * HD_;
    float qv[HD_];
    #pragma unroll
    for (int d = 0; d < HD_; d += 4)
        *(float4*)&qv[d] = *(const float4*)&Q[qrow + d];

    float o[HD_];
    #pragma unroll
    for (int d = 0; d < HD_; ++d) o[d] = 0.f;
    float mrun = -INFINITY, lrun = 0.f;

    // scale = (1/sqrt(64)) * log2(e): do softmax in exp2 domain
    const float scale = 0.125f * 1.44269504088896340736f;

    for (int k0 = 0; k0 < L_; k0 += BKT) {
        __syncthreads();
        // stage K/V tiles (64x64 fp32 each) and mask tile (64 queries x 64 keys)
        #pragma unroll
        for (int it = 0; it < 16; ++it) {
            const int vv = it * 64 + tid;
            const int r  = vv >> 4;          // 0..63
            const int s  = (vv & 15) << 2;   // 0..60
            const size_t g = ((size_t)(b * L_ + k0 + r)) * D_ + h * HD_ + s;
            *(float4*)&Ks[r][s] = *(const float4*)&K[g];
            *(float4*)&Vs[r][s] = *(const float4*)&V[g];
            const int4 mv = *(const int4*)&mask[(size_t)b * L_ * L_ +
                                                (size_t)(q0 + r) * L_ + k0 + s];
            *(int4*)&Ms[r][s] = mv;
        }
        __syncthreads();

        for (int j = 0; j < BKT; ++j) {
            if (Ms[tid][j] != 0) {
                float sc = 0.f;
                #pragma unroll
                for (int d = 0; d < HD_; ++d) sc = fmaf(qv[d], Ks[j][d], sc);
                sc *= scale;  // log2 domain
                float p;
                if (sc > mrun) {
                    const float alpha = exp2f(mrun - sc);  // mrun=-inf -> 0
                    #pragma unroll
                    for (int d = 0; d < HD_; ++d) o[d] *= alpha;
                    lrun *= alpha;
                    mrun = sc;
                    p = 1.f;
                } else {
                    p = exp2f(sc - mrun);
                }
                lrun += p;
                #pragma unroll
                for (int d = 0; d < HD_; ++d) o[d] = fmaf(p, Vs[j][d], o[d]);
            }
        }
    }

    const float rinv = (lrun > 0.f) ? (1.f / lrun) : 0.f;
    #pragma unroll
    for (int d = 0; d < HD_; ++d) o[d] *= rinv;
    float* outp = ctx + qrow;  // same [B,L,D] layout
    #pragma unroll
    for (int d = 0; d < HD_; d += 4)
        *(float4*)&outp[d] = *(const float4*)&o[d];
}

// ---------------------------------------------------------------------------
extern "C" void kernel_launch(void* const* d_in, const int* in_sizes, int n_in,
                              void* d_out, int out_size, void* d_ws, size_t ws_size,
                              hipStream_t stream)
{
    const float* q    = (const float*)d_in[0];
    const float* k    = (const float*)d_in[1];
    const float* v    = (const float*)d_in[2];
    const int*   mask = (const int*)d_in[3];
    const float* WQ   = (const float*)d_in[4];
    const float* bQ   = (const float*)d_in[5];
    const float* WK   = (const float*)d_in[6];
    const float* bK   = (const float*)d_in[7];
    const float* WV   = (const float*)d_in[8];
    const float* bV   = (const float*)d_in[9];
    const float* WO   = (const float*)d_in[10];
    const float* bO   = (const float*)d_in[11];
    float* out = (float*)d_out;

    const size_t NTOK = (size_t)B_ * L_;        // 8192 rows
    const size_t SZ   = NTOK * D_;              // 8M floats = 32 MiB
    float* Qp = (float*)d_ws;
    float* Kp = Qp + SZ;
    float* Vp = Kp + SZ;
    float* Cp = Vp + SZ;                        // total 128 MiB of d_ws

    dim3 gblk(256);
    dim3 ggrd(D_ / GBN, NTOK / GBM);            // (8, 64)

    gemm_bias_kernel<<<ggrd, gblk, 0, stream>>>(q, WQ, bQ, Qp, (int)NTOK, D_, D_);
    gemm_bias_kernel<<<ggrd, gblk, 0, stream>>>(k, WK, bK, Kp, (int)NTOK, D_, D_);
    gemm_bias_kernel<<<ggrd, gblk, 0, stream>>>(v, WV, bV, Vp, (int)NTOK, D_, D_);

    dim3 agrd(L_ / BQ, H_, B_);                 // (32, 16, 4)
    attn_kernel<<<agrd, dim3(BQ), 0, stream>>>(Qp, Kp, Vp, mask, Cp);

    gemm_bias_kernel<<<ggrd, gblk, 0, stream>>>(Cp, WO, bO, out, (int)NTOK, D_, D_);
}

// Round 2
// 2334.002 us; speedup vs baseline: 3.0920x; 3.0920x over previous
//
#include <hip/hip_runtime.h>
#include <math.h>

// Problem constants
#define B_  4
#define L_  2048
#define D_  1024
#define H_  16
#define HD_ 64

// ---------------------------------------------------------------------------
// GEMM: C[M,N] = A[M,K] @ W[K,N] + bias[N]     (all fp32, row-major)
// 128x128 block tile, BK=16, 256 threads, 8x8 micro-tile per thread.
// ---------------------------------------------------------------------------
#define GBM 128
#define GBN 128
#define GBK 16

__global__ __launch_bounds__(256) void gemm_bias_kernel(
    const float* __restrict__ A, const float* __restrict__ W,
    const float* __restrict__ bias, float* __restrict__ C,
    int M, int N, int K)
{
    __shared__ __align__(16) float As[GBK][GBM + 4];  // transposed A tile
    __shared__ __align__(16) float Bs[GBK][GBN + 4];

    const int tid = threadIdx.x;
    const int m0 = blockIdx.y * GBM;
    const int n0 = blockIdx.x * GBN;
    const int tx = tid & 15;
    const int ty = tid >> 4;

    float acc[8][8];
    #pragma unroll
    for (int i = 0; i < 8; ++i)
        #pragma unroll
        for (int j = 0; j < 8; ++j) acc[i][j] = 0.f;

    const int ar0 = tid >> 2;                const int as0 = (tid & 3) << 2;
    const int ar1 = (tid + 256) >> 2;        const int as1 = as0;
    const int br0 = tid >> 5;                const int bc0 = (tid & 31) << 2;
    const int br1 = (tid + 256) >> 5;        const int bc1 = bc0;

    for (int k0 = 0; k0 < K; k0 += GBK) {
        float4 a0 = *(const float4*)&A[(size_t)(m0 + ar0) * K + k0 + as0];
        float4 a1 = *(const float4*)&A[(size_t)(m0 + ar1) * K + k0 + as1];
        float4 b0 = *(const float4*)&W[(size_t)(k0 + br0) * N + n0 + bc0];
        float4 b1 = *(const float4*)&W[(size_t)(k0 + br1) * N + n0 + bc1];

        __syncthreads();
        As[as0 + 0][ar0] = a0.x; As[as0 + 1][ar0] = a0.y;
        As[as0 + 2][ar0] = a0.z; As[as0 + 3][ar0] = a0.w;
        As[as1 + 0][ar1] = a1.x; As[as1 + 1][ar1] = a1.y;
        As[as1 + 2][ar1] = a1.z; As[as1 + 3][ar1] = a1.w;
        *(float4*)&Bs[br0][bc0] = b0;
        *(float4*)&Bs[br1][bc1] = b1;
        __syncthreads();

        #pragma unroll
        for (int kk = 0; kk < GBK; ++kk) {
            float av[8], bv[8];
            *(float4*)&av[0] = *(const float4*)&As[kk][ty * 8];
            *(float4*)&av[4] = *(const float4*)&As[kk][ty * 8 + 4];
            *(float4*)&bv[0] = *(const float4*)&Bs[kk][tx * 8];
            *(float4*)&bv[4] = *(const float4*)&Bs[kk][tx * 8 + 4];
            #pragma unroll
            for (int i = 0; i < 8; ++i)
                #pragma unroll
                for (int j = 0; j < 8; ++j)
                    acc[i][j] = fmaf(av[i], bv[j], acc[i][j]);
        }
    }

    #pragma unroll
    for (int i = 0; i < 8; ++i) {
        const size_t row = (size_t)(m0 + ty * 8 + i) * N + n0 + tx * 8;
        float4 o0, o1;
        o0.x = acc[i][0] + bias[n0 + tx * 8 + 0];
        o0.y = acc[i][1] + bias[n0 + tx * 8 + 1];
        o0.z = acc[i][2] + bias[n0 + tx * 8 + 2];
        o0.w = acc[i][3] + bias[n0 + tx * 8 + 3];
        o1.x = acc[i][4] + bias[n0 + tx * 8 + 4];
        o1.y = acc[i][5] + bias[n0 + tx * 8 + 5];
        o1.z = acc[i][6] + bias[n0 + tx * 8 + 6];
        o1.w = acc[i][7] + bias[n0 + tx * 8 + 7];
        *(float4*)&C[row]     = o0;
        *(float4*)&C[row + 4] = o1;
    }
}

// ---------------------------------------------------------------------------
// Pack mask ints -> bitmask. mbits[(b*L + q)*64 + k/32] bit (k%32).
// One thread per mask element; wave ballot; lanes 0 and 32 write words.
// ---------------------------------------------------------------------------
__global__ __launch_bounds__(256) void pack_mask_kernel(
    const int* __restrict__ mask, unsigned int* __restrict__ mbits)
{
    const int g = blockIdx.x * 256 + threadIdx.x;
    const int v = mask[g];
    const unsigned long long bm = __ballot(v != 0);
    const int lane = threadIdx.x & 63;
    if (lane == 0)       mbits[g >> 5] = (unsigned int)bm;
    else if (lane == 32) mbits[g >> 5] = (unsigned int)(bm >> 32);
}

// ---------------------------------------------------------------------------
// Flash attention v2 (fp32). Block = 256 threads (4 waves), BQ=256 queries,
// one query row per thread. K/V 64x64 tiles in LDS via global_load_lds.
// Branchless online softmax in exp2 domain, 8-key chunks (8-way ILP).
// Q,K,V,ctx layout: [B, L, H*HD].
// ---------------------------------------------------------------------------
#define BQ  256
#define BKT 64

__device__ static inline void async_copy16(const void* g, void* lds)
{
    __builtin_amdgcn_global_load_lds(
        (const __attribute__((address_space(1))) void*)g,
        (__attribute__((address_space(3))) void*)lds, 16, 0, 0);
}

__global__ __launch_bounds__(256, 2) void attn_kernel(
    const float* __restrict__ Q, const float* __restrict__ K,
    const float* __restrict__ V, const unsigned int* __restrict__ mbits,
    float* __restrict__ ctx)
{
    __shared__ __align__(16) float Ks[BKT][HD_];   // 16 KB, unpadded (broadcast reads)
    __shared__ __align__(16) float Vs[BKT][HD_];   // 16 KB

    const int tid  = threadIdx.x;
    const int lane = tid & 63;
    const int wv   = tid >> 6;           // wave id 0..3
    const int q0   = blockIdx.x * BQ;
    const int h    = blockIdx.y;
    const int b    = blockIdx.z;
    const int q    = q0 + tid;

    const size_t qrow = ((size_t)(b * L_ + q)) * D_ + h * HD_;
    float4 qv4[16];
    #pragma unroll
    for (int d4 = 0; d4 < 16; ++d4)
        qv4[d4] = *(const float4*)&Q[qrow + d4 * 4];

    float4 o4[16];
    #pragma unroll
    for (int d4 = 0; d4 < 16; ++d4) o4[d4] = make_float4(0.f, 0.f, 0.f, 0.f);
    float mrun = -INFINITY, lrun = 0.f;

    // 1/sqrt(64) * log2(e): softmax in exp2 domain
    const float scale = 0.125f * 1.44269504088896340736f;

    const unsigned int* mrow = mbits + ((size_t)(b * L_ + q)) * (L_ / 32);

    for (int kt = 0; kt < L_ / BKT; ++kt) {
        const int k0 = kt * BKT;
        __syncthreads();   // previous tile's LDS reads complete
        // async stage K/V tile: 1024 float4 each, wave wv handles f = i*256+wv*64+lane
        #pragma unroll
        for (int i = 0; i < 4; ++i) {
            const int fb = i * 256 + wv * 64;         // wave-uniform float4 base
            const int f  = fb + lane;
            const int r  = f >> 4;
            const int c4 = (f & 15) << 2;
            const size_t g = ((size_t)(b * L_ + k0 + r)) * D_ + h * HD_ + c4;
            async_copy16(&K[g], (char*)&Ks[0][0] + fb * 16);
            async_copy16(&V[g], (char*)&Vs[0][0] + fb * 16);
        }
        const uint2 mw = *(const uint2*)&mrow[kt * 2];
        const unsigned long long mb =
            ((unsigned long long)mw.y << 32) | (unsigned long long)mw.x;
        __syncthreads();   // drains vmcnt: LDS tile ready

        for (int c = 0; c < 8; ++c) {              // 8 chunks of 8 keys
            const int jb = c * 8;
            float s[8];
            #pragma unroll
            for (int jj = 0; jj < 8; ++jj) s[jj] = 0.f;

            #pragma unroll
            for (int d4 = 0; d4 < 16; ++d4) {
                const float4 qq = qv4[d4];
                #pragma unroll
                for (int jj = 0; jj < 8; ++jj) {
                    const float4 kk = *(const float4*)&Ks[jb + jj][d4 * 4];
                    s[jj] = fmaf(qq.x, kk.x, s[jj]);
                    s[jj] = fmaf(qq.y, kk.y, s[jj]);
                    s[jj] = fmaf(qq.z, kk.z, s[jj]);
                    s[jj] = fmaf(qq.w, kk.w, s[jj]);
                }
            }

            float cmax = -INFINITY;
            #pragma unroll
            for (int jj = 0; jj < 8; ++jj) {
                const bool on = (mb >> (jb + jj)) & 1ull;
                s[jj] = on ? s[jj] * scale : -INFINITY;
                cmax = fmaxf(cmax, s[jj]);
            }

            const float mnew  = fmaxf(mrun, cmax);
            const float msafe = fmaxf(mnew, -1e30f);   // avoid inf-inf
            const float alpha = exp2f(mrun - msafe);   // mrun=-inf -> 0 (o,l are 0)
            float pr[8], psum = 0.f;
            #pragma unroll
            for (int jj = 0; jj < 8; ++jj) {
                pr[jj] = exp2f(s[jj] - msafe);         // masked -> exp2(-inf)=0
                psum += pr[jj];
            }
            lrun = lrun * alpha + psum;
            mrun = mnew;

            #pragma unroll
            for (int d4 = 0; d4 < 16; ++d4) {
                float4 ov = o4[d4];
                ov.x *= alpha; ov.y *= alpha; ov.z *= alpha; ov.w *= alpha;
                #pragma unroll
                for (int jj = 0; jj < 8; ++jj) {
                    const float4 vv = *(const float4*)&Vs[jb + jj][d4 * 4];
                    ov.x = fmaf(pr[jj], vv.x, ov.x);
                    ov.y = fmaf(pr[jj], vv.y, ov.y);
                    ov.z = fmaf(pr[jj], vv.z, ov.z);
                    ov.w = fmaf(pr[jj], vv.w, ov.w);
                }
                o4[d4] = ov;
            }
        }
    }

    const float rinv = (lrun > 0.f) ? (1.f / lrun) : 0.f;
    float* outp = ctx + qrow;
    #pragma unroll
    for (int d4 = 0; d4 < 16; ++d4) {
        float4 ov = o4[d4];
        ov.x *= rinv; ov.y *= rinv; ov.z *= rinv; ov.w *= rinv;
        *(float4*)&outp[d4 * 4] = ov;
    }
}

// ---------------------------------------------------------------------------
extern "C" void kernel_launch(void* const* d_in, const int* in_sizes, int n_in,
                              void* d_out, int out_size, void* d_ws, size_t ws_size,
                              hipStream_t stream)
{
    const float* q    = (const float*)d_in[0];
    const float* k    = (const float*)d_in[1];
    const float* v    = (const float*)d_in[2];
    const int*   mask = (const int*)d_in[3];
    const float* WQ   = (const float*)d_in[4];
    const float* bQ   = (const float*)d_in[5];
    const float* WK   = (const float*)d_in[6];
    const float* bK   = (const float*)d_in[7];
    const float* WV   = (const float*)d_in[8];
    const float* bV   = (const float*)d_in[9];
    const float* WO   = (const float*)d_in[10];
    const float* bO   = (const float*)d_in[11];
    float* out = (float*)d_out;

    const size_t NTOK = (size_t)B_ * L_;        // 8192 rows
    const size_t SZ   = NTOK * D_;              // 8M floats = 32 MiB
    float* Qp = (float*)d_ws;
    float* Kp = Qp + SZ;
    float* Vp = Kp + SZ;
    float* Cp = Vp + SZ;                        // 128 MiB

    // mask bitmask: 2 MiB. Use ws tail if it fits, else borrow d_out
    // (d_out is fully overwritten by the final GEMM after attention).
    const size_t MBW = (size_t)B_ * L_ * (L_ / 32);   // uint32 words
    unsigned int* mbits;
    if (ws_size >= 4 * SZ * sizeof(float) + MBW * sizeof(unsigned int))
        mbits = (unsigned int*)(Cp + SZ);
    else
        mbits = (unsigned int*)d_out;

    pack_mask_kernel<<<(B_ * L_ * L_) / 256, 256, 0, stream>>>(mask, mbits);

    dim3 gblk(256);
    dim3 ggrd(D_ / GBN, NTOK / GBM);            // (8, 64)
    gemm_bias_kernel<<<ggrd, gblk, 0, stream>>>(q, WQ, bQ, Qp, (int)NTOK, D_, D_);
    gemm_bias_kernel<<<ggrd, gblk, 0, stream>>>(k, WK, bK, Kp, (int)NTOK, D_, D_);
    gemm_bias_kernel<<<ggrd, gblk, 0, stream>>>(v, WV, bV, Vp, (int)NTOK, D_, D_);

    dim3 agrd(L_ / BQ, H_, B_);                 // (8, 16, 4)
    attn_kernel<<<agrd, dim3(256), 0, stream>>>(Qp, Kp, Vp, mbits, Cp);

    gemm_bias_kernel<<<ggrd, gblk, 0, stream>>>(Cp, WO, bO, out, (int)NTOK, D_, D_);
}